// Round 9
// baseline (122.634 us; speedup 1.0000x reference)
//
#include <hip/hip_runtime.h>
#include <hip/hip_fp16.h>

// DFMB PSROIAlign — fp16 row-line layout + wave-cooperative quarter-split
// gathers.
//
// Model (R8-R16, fitted): main is pinned by L1/TCP lookup THROUGHPUT —
// ~1 distinct-line lookup per cycle per gather instruction. Old path: each
// lane loads its own 64B row-line as 4 x b128 -> every instruction = 64
// distinct lines, and each line is charged 4x (one per b128). 90K cyc/CU.
// R16 proved it's throughput, not latency (depth-1 pipeline was null vs R9).
// Sorting shares lines but every delivery mechanism cost >= its gain
// (R11-R15). Floor = touch each line once = 22.5K cyc/CU (~7.2us).
//
// R17: quarter-split cooperative gather, no sorting. Per wave / bin-group j /
// patch-row p: instruction i (i=0..3): lane L loads quarter (L&3) of the
// line owned by lane src=i*16+(L>>2) (addr via __shfl), ds_write_b128 into a
// per-wave stage buffer (64 slots x 20dw, 16B-aligned, quarter-XOR
// ((slot>>3)&3) -> per-bank depth exactly 8 = minimum, balanced), then lane
// reads its own line back (4 x ds_read_b128, balanced). Distinct lines per
// gather instr: 64 -> 16. Lookups/wave-j: 768 -> 192 (floor). FMA order
// unchanged -> bit-identical output. LDS 59KB -> 2 blocks/CU.
//
// Row-line layout (R10, verified R10-R16): 3 phase copies of 64B lines;
// copy m line g = pixels [3g+m..3g+m+2] x 10ch fp16 (60B)+pad dword (pad is
// never FMA'd; it transits LDS as raw u32 only). Window at pixel fp = ONE
// line (m=fp%3, g=fp/3). Column clamp merged into element weights.
// NaN safety: prep writes all 15 data dwords of every line incl. 2 zero tail
// pixels; masked/invalid lanes use line 0 with ew=0.

#define NC 10
#define NBIN 49
#define FH 34
#define FW 34
#define PLANE (FH * FW)
#define NPIX (NBIN * PLANE)  // 56644
#define GPC 18882            // row-lines per phase copy
#define RPB 16               // rois per block
#define TSTRIDE 491          // out-tile row stride (odd -> conflict-free flush)
#define NSIDE 14
#define SLOTW 20             // dwords per stage slot (80B, 16B-aligned quarters)

__device__ __forceinline__ void pack_pixel(
    const float* __restrict__ ft, unsigned int* __restrict__ ftR, int p)
{
    unsigned int h2[5];
    if (p < NPIX) {
#pragma unroll
        for (int c = 0; c < 5; ++c) {
            const __half lo = __float2half_rn(ft[(2 * c)     * NPIX + p]);
            const __half hi = __float2half_rn(ft[(2 * c + 1) * NPIX + p]);
            const __half2 hh = __halves2half2(lo, hi);
            h2[c] = *(const unsigned int*)&hh;
        }
    } else {
#pragma unroll
        for (int c = 0; c < 5; ++c) h2[c] = 0u;  // tail: finite zeros
    }
    // pixel p -> copy m (m<=p), line g=(p-m)/3, slot j=(p-m)%3
#pragma unroll
    for (int m = 0; m < 3; ++m) {
        if (p >= m) {
            const int t = p - m;
            const int g = t / 3;
            const int j = t - 3 * g;
            if (g < GPC) {
                unsigned int* d = ftR + ((size_t)m * GPC + g) * 16 + j * 5;
#pragma unroll
                for (int c = 0; c < 5; ++c) d[c] = h2[c];
            }
        }
    }
}

__global__ __launch_bounds__(1024) void prep_kernel(
    const float* __restrict__ ft, unsigned int* __restrict__ ftR)
{
    const int p = blockIdx.x * 1024 + threadIdx.x;
    if (p < NPIX + 2) pack_pixel(ft, ftR, p);
}

__device__ __forceinline__ void fma2(float w, unsigned int u, float& s0, float& s1)
{
    const __half2 h = *(const __half2*)&u;
    s0 = fmaf(w, __half2float(__low2half(h)),  s0);   // -> v_fma_mix_f32
    s1 = fmaf(w, __half2float(__high2half(h)), s1);
}

// metadata for bin (J*RPB+s): element weights EW[3][3] (column-clamp merged,
// zeroed when bin invalid), row line-start pixels FP[3] (0 when invalid,
// binbase dummy for zero-weight rows), INV = 1/count, store guard BVV.
#define BIN_META(J, EW, FP, INV, BINV, BVV)                                    \
    {                                                                          \
        BINV = (J) * RPB + s;                                                  \
        BVV = valid && (BINV < NBIN);                                          \
        const float msk = BVV ? 1.0f : 0.0f;                                   \
        const int ph = BINV / 7;                                               \
        const int pw = BINV - ph * 7;                                          \
        const float4 ya = *(const float4*)&sides[ph][r][0];                    \
        const float4 yb = *(const float4*)&sides[ph][r][4];                    \
        const float4 xa = *(const float4*)&sides[7 + pw][r][0];                \
        const float4 xb = *(const float4*)&sides[7 + pw][r][4];                \
        const float AY[3] = {ya.x, ya.y, ya.z};                                \
        const float BY[3] = {ya.w, yb.x, yb.y};                                \
        const float AX[3] = {xa.x, xa.y, xa.z};                                \
        const float BX[3] = {xa.w, xb.x, xb.y};                                \
        const int Y0 = (int)yb.w;                                              \
        const int X0 = (int)xb.w;                                              \
        const float cnt = yb.z * xb.z;                                         \
        INV = (cnt > 0.0f) ? __fdiv_rn(1.0f, cnt) : 1.0f;                      \
        const int binbase = BINV * PLANE;                                      \
        const int rowo[3] = {binbase + Y0 * FW,                                \
                             binbase + min(Y0 + 1, FH - 1) * FW,               \
                             binbase + min(Y0 + 2, FH - 1) * FW};              \
        const int e = (FW - 1) - X0;                                           \
        _Pragma("unroll") for (int p = 0; p < 3; ++p) {                        \
            const float w0 = (AY[p] * AX[0] - BY[p] * BX[0]) * msk;            \
            const float w1 = (AY[p] * AX[1] - BY[p] * BX[1]) * msk;            \
            const float w2 = (AY[p] * AX[2] - BY[p] * BX[2]) * msk;            \
            const float s12 = w1 + w2;                                         \
            EW[p][0] = (e < 1) ? (w0 + s12) : w0;                              \
            EW[p][1] = (e < 1) ? 0.f : ((e < 2) ? s12 : w1);                   \
            EW[p][2] = (e < 2) ? 0.f : w2;                                     \
            const bool rnz = (w0 != 0.0f) || (w1 != 0.0f) || (w2 != 0.0f);     \
            FP[p] = BVV ? (rnz ? (rowo[p] + X0) : binbase) : 0;                \
        }                                                                      \
    }

__global__ __launch_bounds__(256, 2) void main_kernel(
    const float* __restrict__ rois, const unsigned int* __restrict__ ftR,
    const float* __restrict__ ft, float* __restrict__ out, int N, int use_t)
{
    __shared__ float sides[NSIDE][RPB][8];          // 7 KB
    __shared__ float tile[RPB][TSTRIDE];            // 31.4 KB
    __shared__ unsigned int stage[4][64 * SLOTW];   // 20 KB (per-wave)

    const int r = threadIdx.x & (RPB - 1);  // roi within block
    const int s = threadIdx.x >> 4;         // slot 0..15
    const int n = blockIdx.x * RPB + r;
    const bool valid = (n < N);

    float rsw = 0.f, rsh = 0.f, rew = 0.f, reh = 0.f;
    if (valid) {
        rsw = rois[n * 5 + 1] * 0.125f;  // /STRIDE(8), exact pow2
        rsh = rois[n * 5 + 2] * 0.125f;
        rew = rois[n * 5 + 3] * 0.125f;
        reh = rois[n * 5 + 4] * 0.125f;
    }
    // Explicit _rn chain: floor/ceil/compare inputs must bit-match numpy fp32.
    float rheight = __fsub_rn(reh, rsh);
    if (!(rheight > 0.1f)) rheight = 0.1f;
    float rwidth = __fsub_rn(rew, rsw);
    if (!(rwidth > 0.1f)) rwidth = 0.1f;
    const float bsh   = __fdiv_rn(rheight, 7.0f);
    const float bsw   = __fdiv_rn(rwidth, 7.0f);
    const float sub_h = __fdiv_rn(bsh, 4.0f);
    const float sub_w = __fdiv_rn(bsw, 4.0f);

    // ---- phase 1: one axis-side per slot (slots 0..13 active) ----
    if (s < NSIDE) {
        const bool isY = (s < 7);
        const int  k   = isY ? s : s - 7;
        const float st = isY ? rsh : rsw;
        const float bs = isY ? bsh : bsw;
        const float sb = isY ? sub_h : sub_w;
        const float start = floorf(__fadd_rn(st, __fmul_rn((float)k, bs)));

        float A[3] = {0.f, 0.f, 0.f}, B[3] = {0.f, 0.f, 0.f};
        float cnt = 0.f;
        int P0 = 0;
#pragma unroll
        for (int i = 0; i < 4; ++i) {
            const float h = __fadd_rn(start, __fmul_rn((float)i + 0.5f, sb));
            const bool ok = (h > -1.0f) && (h < 34.0f);
            const int p1 = (int)floorf(h);
            const int p2 = (int)ceilf(h);
            const bool v1 = (p1 >= 0) && (p1 < 34);
            const bool v2 = (p2 >= 0) && (p2 < 34);
            const int p1c = min(max(p1, 0), 33);
            const int p2c = min(max(p2, 0), 33);
            const float d = __fsub_rn(h, (float)p1c);  // vs CLIPPED corner
            if (i == 0) P0 = p1c;                      // min (h increasing)
            const int i1 = p1c - P0, i2 = p2c - P0;    // in {0,1,2}
            const float t1 = ok ? (1.0f - d) : 0.0f;
            const float t2 = ok ? d : 0.0f;
            // bad11 = (!x1v || !x2v) && (y1v || y2v): X carries "invalid",
            // Y carries "valid".
            const bool bsel = isY ? (v1 || v2) : ((!v1) || (!v2));
            const float tb = (ok && bsel) ? (1.0f - d) : 0.0f;
            cnt += ok ? 1.0f : 0.0f;
#pragma unroll
            for (int p = 0; p < 3; ++p) {
                A[p] += (i1 == p) ? t1 : 0.0f;
                A[p] += (i2 == p) ? t2 : 0.0f;
                B[p] += (i1 == p) ? tb : 0.0f;
            }
        }
        float* sp = &sides[s][r][0];
        sp[0] = A[0]; sp[1] = A[1]; sp[2] = A[2];
        sp[3] = B[0]; sp[4] = B[1]; sp[5] = B[2];
        sp[6] = cnt;  sp[7] = (float)P0;
    }
    __syncthreads();

    // ---- phase 2: 4 bins/thread; cooperative quarter-split gathers ----
    if (use_t) {
        const int L = threadIdx.x & 63;                  // lane in wave
        unsigned int* sw = &stage[threadIdx.x >> 6][0];  // per-wave buffer
#pragma unroll
        for (int j = 0; j < 4; ++j) {
            float ew[3][3];
            int   fp[3];
            float inv;
            int   binv;
            bool  bvv;
            BIN_META(j, ew, fp, inv, binv, bvv);

            int adw[3];  // dword base address of each row's line
#pragma unroll
            for (int p = 0; p < 3; ++p) {
                const int g = fp[p] / 3;
                const int m = fp[p] - 3 * g;
                adw[p] = (m * GPC + g) * 16;
            }

            float sum[NC];
#pragma unroll
            for (int c = 0; c < NC; ++c) sum[c] = 0.f;

#pragma unroll
            for (int p = 0; p < 3; ++p) {
                // cooperative load: instr i covers 16 lines, 4 lanes/line.
                // dst swizzle: quarter q of slot t at t*20 + 4*(q^((t>>3)&3))
                // -> per-bank depth exactly 8 (balanced) for writes AND reads.
#pragma unroll
                for (int i = 0; i < 4; ++i) {
                    const int src = i * 16 + (L >> 2);
                    const int a   = __shfl(adw[p], src, 64);
                    const uint4 v = *(const uint4*)(ftR + a + (L & 3) * 4);
                    const int dst = src * SLOTW + 4 * ((L & 3) ^ ((src >> 3) & 3));
                    *(uint4*)(sw + dst) = v;
                }
                // read own line back (quarter k at L*20 + 4*(k^((L>>3)&3)))
                unsigned int rv[16];
#pragma unroll
                for (int k = 0; k < 4; ++k) {
                    const int rd = L * SLOTW + 4 * (k ^ ((L >> 3) & 3));
                    const uint4 u = *(const uint4*)(sw + rd);
                    rv[4 * k]     = u.x;
                    rv[4 * k + 1] = u.y;
                    rv[4 * k + 2] = u.z;
                    rv[4 * k + 3] = u.w;  // k=3: dw15 = pad, never FMA'd
                }
                // FMA row p (order identical to R9-R16: p outer, c inner)
#pragma unroll
                for (int c = 0; c < 5; ++c) {
                    fma2(ew[p][0], rv[c],      sum[2 * c], sum[2 * c + 1]);
                    fma2(ew[p][1], rv[5 + c],  sum[2 * c], sum[2 * c + 1]);
                    fma2(ew[p][2], rv[10 + c], sum[2 * c], sum[2 * c + 1]);
                }
            }

            if (bvv) {
                float* tp = &tile[r][0];
#pragma unroll
                for (int c = 0; c < NC; ++c) tp[c * NBIN + binv] = sum[c] * inv;
            }
        }
    } else {
        // fallback: direct fp32 gathers from ft
#pragma unroll
        for (int j = 0; j < 4; ++j) {
            const int bin = j * RPB + s;
            if (valid && bin < NBIN) {
                const int ph = bin / 7;
                const int pw = bin - ph * 7;
                const float4 ya = *(const float4*)&sides[ph][r][0];
                const float4 yb = *(const float4*)&sides[ph][r][4];
                const float4 xa = *(const float4*)&sides[7 + pw][r][0];
                const float4 xb = *(const float4*)&sides[7 + pw][r][4];
                const float AY[3] = {ya.x, ya.y, ya.z};
                const float BY[3] = {ya.w, yb.x, yb.y};
                const float AX[3] = {xa.x, xa.y, xa.z};
                const float BX[3] = {xa.w, xb.x, xb.y};
                const int Y0 = (int)yb.w, X0 = (int)xb.w;
                const float cnt = yb.z * xb.z;
                const int binbase = bin * PLANE;
                const int rowo[3] = {binbase + Y0 * FW,
                                     binbase + min(Y0 + 1, FH - 1) * FW,
                                     binbase + min(Y0 + 2, FH - 1) * FW};
                const int colo[3] = {X0, min(X0 + 1, FW - 1), min(X0 + 2, FW - 1)};
                float wgt[9];
                int off[9];
#pragma unroll
                for (int p = 0; p < 3; ++p)
#pragma unroll
                    for (int q2 = 0; q2 < 3; ++q2) {
                        const float w = AY[p] * AX[q2] - BY[p] * BX[q2];
                        wgt[3 * p + q2] = w;
                        off[3 * p + q2] = (w != 0.0f) ? (rowo[p] + colo[q2]) : binbase;
                    }
                float sum[NC];
#pragma unroll
                for (int c = 0; c < NC; ++c) sum[c] = 0.f;
#pragma unroll
                for (int k = 0; k < 9; ++k) {
                    const float w = wgt[k];
#pragma unroll
                    for (int c = 0; c < NC; ++c)
                        sum[c] = fmaf(w, ft[c * NPIX + off[k]], sum[c]);
                }
                const float inv = (cnt > 0.0f) ? __fdiv_rn(1.0f, cnt) : 1.0f;
                float* tp = &tile[r][0];
#pragma unroll
                for (int c = 0; c < NC; ++c) tp[c * NBIN + bin] = sum[c] * inv;
            }
        }
    }

    __syncthreads();

    // Coalesced flush: 16 rois x 490 contiguous floats each.
    const int n0 = blockIdx.x * RPB;
    for (int i = threadIdx.x; i < RPB * (NC * NBIN); i += 256) {
        const int row = i / (NC * NBIN);
        const int col = i - row * (NC * NBIN);
        const int n2 = n0 + row;
        if (n2 < N) out[(size_t)n2 * (NC * NBIN) + col] = tile[row][col];
    }
}

extern "C" void kernel_launch(void* const* d_in, const int* in_sizes, int n_in,
                              void* d_out, int out_size, void* d_ws, size_t ws_size,
                              hipStream_t stream) {
    const float* ft   = (const float*)d_in[0];
    const float* rois = (const float*)d_in[1];
    float* out        = (float*)d_out;
    const int N = in_sizes[1] / 5;

    // ws: ftR only (3 copies x GPC x 64B = 3,625,344 B)
    const size_t need = (size_t)3 * GPC * 64;
    const int use_t = (ws_size >= need) ? 1 : 0;
    unsigned int* ftR = (unsigned int*)d_ws;

    if (use_t) {
        prep_kernel<<<(NPIX + 2 + 1023) / 1024, 1024, 0, stream>>>(ft, ftR);
    }
    main_kernel<<<(N + RPB - 1) / RPB, 256, 0, stream>>>(rois, ftR, ft, out, N, use_t);
}

// Round 10
// 109.264 us; speedup vs baseline: 1.1224x; 1.1224x over previous
//
#include <hip/hip_runtime.h>
#include <hip/hip_fp16.h>

// DFMB PSROIAlign — R9 fp16 split layout + R16 depth-1 software pipeline.
//
// Nine-round model: main is pinned by L1 gather throughput (~1 cycle per
// distinct 64B line per gather instruction; 64 lanes = 64 distinct planes
// -> 64 lines/instr, structural without sorting). Both line-sharing families
// failed on delivery cost: sorting (R11-R15: every mechanism >= its gain),
// LDS-cooperative staging (R17: +5.5M bank-conflict cycles, -occupancy).
//
// What verifiably works:
//   R9 layout  (ftA 16B/pixel ch0-7 + ftB 4 phase copies ch8,9): FETCH
//              6.8MB, main 46.3us — best measured.
//   R16 pipeline (branchless A/B depth-1: load(j+1) before fma(j)): -8.1us
//              on the identical R10 layout (55.5 -> 47.4).
// R18 composes them. FMA order identical to R9 -> bit-identical output.
//
// ftA: 16B/pixel (ch0-7 as 4x half2). ftB: ch8,9 as one half2, FOUR
// phase-shifted copies (copy m: element i <- pixel i+m); row window at
// pixel fp = one aligned uint4 from copy m=fp&3 at i0=fp&~3 (V[0..2] =
// pixels fp..fp+2; V.w never FMA'd). Column clamp via index-select
// (u1 = e>=1 ? V[1] : V[0]; u2 = e>=2 ? V[2] : u1), e = 33 - X0.
// Invalid bins (j=3, s>0): wgt=0, off=0/binbase (finite data), store guarded.

#define NC 10
#define NBIN 49
#define FH 34
#define FW 34
#define PLANE (FH * FW)
#define NPIX (NBIN * PLANE)  // 56644, %4==0 (ftB copy alignment)
#define RPB 16               // rois per block
#define TSTRIDE 491          // out-tile row stride (odd -> conflict-free flush)
#define NSIDE 14

__global__ __launch_bounds__(1024) void prep_kernel(
    const float* __restrict__ ft, unsigned int* __restrict__ ws)
{
    const int p = blockIdx.x * 1024 + threadIdx.x;
    if (p >= NPIX) return;
    unsigned int h2[5];
#pragma unroll
    for (int c = 0; c < 5; ++c) {
        const __half lo = __float2half_rn(ft[(2 * c)     * NPIX + p]);
        const __half hi = __float2half_rn(ft[(2 * c + 1) * NPIX + p]);
        const __half2 hh = __halves2half2(lo, hi);
        h2[c] = *(const unsigned int*)&hh;
    }
    // ftA: ch0-7, 16B/pixel
    *(uint4*)(ws + (size_t)p * 4) = make_uint4(h2[0], h2[1], h2[2], h2[3]);
    // ftB: ch8-9, 4 phase-shifted copies; copy m, element i <- pixel i+m
    unsigned int* fb = ws + (size_t)NPIX * 4;
#pragma unroll
    for (int m = 0; m < 4; ++m)
        if (p >= m) fb[(size_t)m * NPIX + (p - m)] = h2[m == 0 ? 4 : 4];  // h2[4]
}

__device__ __forceinline__ void fma2(float w, unsigned int u, float& s0, float& s1)
{
    const __half2 h = *(const __half2*)&u;
    s0 = fmaf(w, __half2float(__low2half(h)),  s0);   // -> v_fma_mix_f32
    s1 = fmaf(w, __half2float(__high2half(h)), s1);
}

// ---- phase-2 pipeline macros (all indices static after unroll) ----

// metadata for bin (J*RPB+s): 9 pixel weights WGT (masked when invalid),
// 9 ftA offsets OFF (binbase dummy for zero weights; 0 when invalid),
// 3 ftB row starts FPB, clamp width E, INV = 1/count, store guard BVV.
#define BIN_META9(J, WGT, OFF, FPB, E, INV, BINV, BVV)                         \
    {                                                                          \
        BINV = (J) * RPB + s;                                                  \
        BVV = valid && (BINV < NBIN);                                          \
        const float msk = BVV ? 1.0f : 0.0f;                                   \
        const int ph = BINV / 7;                                               \
        const int pw = BINV - ph * 7;                                          \
        const float4 ya = *(const float4*)&sides[ph][r][0];                    \
        const float4 yb = *(const float4*)&sides[ph][r][4];                    \
        const float4 xa = *(const float4*)&sides[7 + pw][r][0];                \
        const float4 xb = *(const float4*)&sides[7 + pw][r][4];                \
        const float AY[3] = {ya.x, ya.y, ya.z};                                \
        const float BY[3] = {ya.w, yb.x, yb.y};                                \
        const float AX[3] = {xa.x, xa.y, xa.z};                                \
        const float BX[3] = {xa.w, xb.x, xb.y};                                \
        const int Y0 = (int)yb.w;                                              \
        const int X0 = (int)xb.w;                                              \
        const float cnt = yb.z * xb.z;                                         \
        INV = (cnt > 0.0f) ? __fdiv_rn(1.0f, cnt) : 1.0f;                      \
        const int binbase = BINV * PLANE;                                      \
        const int rowo[3] = {binbase + Y0 * FW,                                \
                             binbase + min(Y0 + 1, FH - 1) * FW,               \
                             binbase + min(Y0 + 2, FH - 1) * FW};              \
        const int colo[3] = {X0, min(X0 + 1, FW - 1), min(X0 + 2, FW - 1)};    \
        E = (FW - 1) - X0;                                                     \
        _Pragma("unroll") for (int p = 0; p < 3; ++p) {                        \
            bool rnz = false;                                                  \
            _Pragma("unroll") for (int q = 0; q < 3; ++q) {                    \
                const float w = (AY[p] * AX[q] - BY[p] * BX[q]) * msk;         \
                WGT[3 * p + q] = w;                                            \
                OFF[3 * p + q] =                                               \
                    BVV ? ((w != 0.0f) ? (rowo[p] + colo[q]) : binbase) : 0;   \
                rnz = rnz || (w != 0.0f);                                      \
            }                                                                  \
            FPB[p] = BVV ? (rnz ? (rowo[p] + X0) : binbase) : 0;               \
        }                                                                      \
    }

// gathers: 9 ftA uint4 + 3 ftB row uint4 (12 b128, as R9)
#define LOAD9(OFF, FPB, VA, VB)                                                \
    {                                                                          \
        _Pragma("unroll") for (int k = 0; k < 9; ++k)                          \
            VA[k] = *(const uint4*)(ftH + (size_t)OFF[k] * 4);                 \
        _Pragma("unroll") for (int p = 0; p < 3; ++p) {                        \
            const int m = FPB[p] & 3;                                          \
            const int i0 = FPB[p] & ~3;                                        \
            VB[p] = *(const uint4*)(fB + (size_t)m * NPIX + i0);               \
        }                                                                      \
    }

// FMA order identical to R9: ftA k=0..8 (sum0..7), then ftB rows (sum8,9)
#define FMA_STORE9(WGT, E, VA, VB, INV, BINV, BVV)                             \
    {                                                                          \
        float sum[NC];                                                         \
        _Pragma("unroll") for (int c = 0; c < NC; ++c) sum[c] = 0.f;           \
        _Pragma("unroll") for (int k = 0; k < 9; ++k) {                        \
            const float w = WGT[k];                                            \
            fma2(w, VA[k].x, sum[0], sum[1]);                                  \
            fma2(w, VA[k].y, sum[2], sum[3]);                                  \
            fma2(w, VA[k].z, sum[4], sum[5]);                                  \
            fma2(w, VA[k].w, sum[6], sum[7]);                                  \
        }                                                                      \
        _Pragma("unroll") for (int p = 0; p < 3; ++p) {                        \
            const unsigned int u0 = VB[p].x;                                   \
            const unsigned int u1 = (E >= 1) ? VB[p].y : VB[p].x;              \
            const unsigned int u2 = (E >= 2) ? VB[p].z : u1;                   \
            fma2(WGT[3 * p + 0], u0, sum[8], sum[9]);                          \
            fma2(WGT[3 * p + 1], u1, sum[8], sum[9]);                          \
            fma2(WGT[3 * p + 2], u2, sum[8], sum[9]);                          \
        }                                                                      \
        if (BVV) {                                                             \
            float* tp = &tile[r][0];                                           \
            _Pragma("unroll") for (int c = 0; c < NC; ++c)                     \
                tp[c * NBIN + BINV] = sum[c] * INV;                            \
        }                                                                      \
    }

__global__ __launch_bounds__(256, 3) void main_kernel(
    const float* __restrict__ rois, const unsigned int* __restrict__ ftH,
    const float* __restrict__ ft, float* __restrict__ out, int N, int use_t)
{
    __shared__ float sides[NSIDE][RPB][8];  // 7 KB
    __shared__ float tile[RPB][TSTRIDE];    // 31.4 KB

    const int r = threadIdx.x & (RPB - 1);  // roi within block
    const int s = threadIdx.x >> 4;         // slot 0..15
    const int n = blockIdx.x * RPB + r;
    const bool valid = (n < N);

    float rsw = 0.f, rsh = 0.f, rew = 0.f, reh = 0.f;
    if (valid) {
        rsw = rois[n * 5 + 1] * 0.125f;  // /STRIDE(8), exact pow2
        rsh = rois[n * 5 + 2] * 0.125f;
        rew = rois[n * 5 + 3] * 0.125f;
        reh = rois[n * 5 + 4] * 0.125f;
    }
    // Explicit _rn chain: floor/ceil/compare inputs must bit-match numpy fp32.
    float rheight = __fsub_rn(reh, rsh);
    if (!(rheight > 0.1f)) rheight = 0.1f;
    float rwidth = __fsub_rn(rew, rsw);
    if (!(rwidth > 0.1f)) rwidth = 0.1f;
    const float bsh   = __fdiv_rn(rheight, 7.0f);
    const float bsw   = __fdiv_rn(rwidth, 7.0f);
    const float sub_h = __fdiv_rn(bsh, 4.0f);
    const float sub_w = __fdiv_rn(bsw, 4.0f);

    // ---- phase 1: one axis-side per slot (slots 0..13 active) ----
    if (s < NSIDE) {
        const bool isY = (s < 7);
        const int  k   = isY ? s : s - 7;
        const float st = isY ? rsh : rsw;
        const float bs = isY ? bsh : bsw;
        const float sb = isY ? sub_h : sub_w;
        const float start = floorf(__fadd_rn(st, __fmul_rn((float)k, bs)));

        float A[3] = {0.f, 0.f, 0.f}, B[3] = {0.f, 0.f, 0.f};
        float cnt = 0.f;
        int P0 = 0;
#pragma unroll
        for (int i = 0; i < 4; ++i) {
            const float h = __fadd_rn(start, __fmul_rn((float)i + 0.5f, sb));
            const bool ok = (h > -1.0f) && (h < 34.0f);
            const int p1 = (int)floorf(h);
            const int p2 = (int)ceilf(h);
            const bool v1 = (p1 >= 0) && (p1 < 34);
            const bool v2 = (p2 >= 0) && (p2 < 34);
            const int p1c = min(max(p1, 0), 33);
            const int p2c = min(max(p2, 0), 33);
            const float d = __fsub_rn(h, (float)p1c);  // vs CLIPPED corner
            if (i == 0) P0 = p1c;                      // min (h increasing)
            const int i1 = p1c - P0, i2 = p2c - P0;    // in {0,1,2}
            const float t1 = ok ? (1.0f - d) : 0.0f;
            const float t2 = ok ? d : 0.0f;
            // bad11 = (!x1v || !x2v) && (y1v || y2v): X carries "invalid",
            // Y carries "valid".
            const bool bsel = isY ? (v1 || v2) : ((!v1) || (!v2));
            const float tb = (ok && bsel) ? (1.0f - d) : 0.0f;
            cnt += ok ? 1.0f : 0.0f;
#pragma unroll
            for (int p = 0; p < 3; ++p) {
                A[p] += (i1 == p) ? t1 : 0.0f;
                A[p] += (i2 == p) ? t2 : 0.0f;
                B[p] += (i1 == p) ? tb : 0.0f;
            }
        }
        float* sp = &sides[s][r][0];
        sp[0] = A[0]; sp[1] = A[1]; sp[2] = A[2];
        sp[3] = B[0]; sp[4] = B[1]; sp[5] = B[2];
        sp[6] = cnt;  sp[7] = (float)P0;
    }
    __syncthreads();

    // ---- phase 2: depth-1 pipelined, 4 bins/thread, 12 b128/bin ----
    if (use_t) {
        const unsigned int* fB = ftH + (size_t)NPIX * 4;
        float wgtA[9], wgtB[9];
        int   offA[9], offB[9];
        int   fpbA[3], fpbB[3];
        int   eA, eB, binA, binB;
        float invA, invB;
        bool  bvA, bvB;
        uint4 vaA[9], vaB[9];
        uint4 vbA[3], vbB[3];

        BIN_META9(0, wgtA, offA, fpbA, eA, invA, binA, bvA);
        LOAD9(offA, fpbA, vaA, vbA);
        BIN_META9(1, wgtB, offB, fpbB, eB, invB, binB, bvB);
        LOAD9(offB, fpbB, vaB, vbB);
        FMA_STORE9(wgtA, eA, vaA, vbA, invA, binA, bvA);
        BIN_META9(2, wgtA, offA, fpbA, eA, invA, binA, bvA);
        LOAD9(offA, fpbA, vaA, vbA);
        FMA_STORE9(wgtB, eB, vaB, vbB, invB, binB, bvB);
        BIN_META9(3, wgtB, offB, fpbB, eB, invB, binB, bvB);
        LOAD9(offB, fpbB, vaB, vbB);
        FMA_STORE9(wgtA, eA, vaA, vbA, invA, binA, bvA);
        FMA_STORE9(wgtB, eB, vaB, vbB, invB, binB, bvB);
    } else {
        // fallback: direct fp32 gathers from ft
#pragma unroll
        for (int j = 0; j < 4; ++j) {
            const int bin = j * RPB + s;
            if (valid && bin < NBIN) {
                const int ph = bin / 7;
                const int pw = bin - ph * 7;
                const float4 ya = *(const float4*)&sides[ph][r][0];
                const float4 yb = *(const float4*)&sides[ph][r][4];
                const float4 xa = *(const float4*)&sides[7 + pw][r][0];
                const float4 xb = *(const float4*)&sides[7 + pw][r][4];
                const float AY[3] = {ya.x, ya.y, ya.z};
                const float BY[3] = {ya.w, yb.x, yb.y};
                const float AX[3] = {xa.x, xa.y, xa.z};
                const float BX[3] = {xa.w, xb.x, xb.y};
                const int Y0 = (int)yb.w, X0 = (int)xb.w;
                const float cnt = yb.z * xb.z;
                const int binbase = bin * PLANE;
                const int rowo[3] = {binbase + Y0 * FW,
                                     binbase + min(Y0 + 1, FH - 1) * FW,
                                     binbase + min(Y0 + 2, FH - 1) * FW};
                const int colo[3] = {X0, min(X0 + 1, FW - 1), min(X0 + 2, FW - 1)};
                float wgt[9];
                int off[9];
#pragma unroll
                for (int p = 0; p < 3; ++p)
#pragma unroll
                    for (int q2 = 0; q2 < 3; ++q2) {
                        const float w = AY[p] * AX[q2] - BY[p] * BX[q2];
                        wgt[3 * p + q2] = w;
                        off[3 * p + q2] = (w != 0.0f) ? (rowo[p] + colo[q2]) : binbase;
                    }
                float sum[NC];
#pragma unroll
                for (int c = 0; c < NC; ++c) sum[c] = 0.f;
#pragma unroll
                for (int k = 0; k < 9; ++k) {
                    const float w = wgt[k];
#pragma unroll
                    for (int c = 0; c < NC; ++c)
                        sum[c] = fmaf(w, ft[c * NPIX + off[k]], sum[c]);
                }
                const float inv = (cnt > 0.0f) ? __fdiv_rn(1.0f, cnt) : 1.0f;
                float* tp = &tile[r][0];
#pragma unroll
                for (int c = 0; c < NC; ++c) tp[c * NBIN + bin] = sum[c] * inv;
            }
        }
    }

    __syncthreads();

    // Coalesced flush: 16 rois x 490 contiguous floats each.
    const int n0 = blockIdx.x * RPB;
    for (int i = threadIdx.x; i < RPB * (NC * NBIN); i += 256) {
        const int row = i / (NC * NBIN);
        const int col = i - row * (NC * NBIN);
        const int n2 = n0 + row;
        if (n2 < N) out[(size_t)n2 * (NC * NBIN) + col] = tile[row][col];
    }
}

extern "C" void kernel_launch(void* const* d_in, const int* in_sizes, int n_in,
                              void* d_out, int out_size, void* d_ws, size_t ws_size,
                              hipStream_t stream) {
    const float* ft   = (const float*)d_in[0];
    const float* rois = (const float*)d_in[1];
    float* out        = (float*)d_out;
    const int N = in_sizes[1] / 5;

    // ws: ftA (16B/pixel) + 4 ftB copies (4B/pixel each) = 1,812,608 B
    const size_t need = (size_t)NPIX * 16 + (size_t)4 * NPIX * 4;
    const int use_t = (ws_size >= need) ? 1 : 0;
    unsigned int* ftH = (unsigned int*)d_ws;

    if (use_t) {
        prep_kernel<<<(NPIX + 1023) / 1024, 1024, 0, stream>>>(ft, ftH);
    }
    main_kernel<<<(N + RPB - 1) / RPB, 256, 0, stream>>>(rois, ftH, ft, out, N, use_t);
}